// Round 1
// baseline (1565.696 us; speedup 1.0000x reference)
//
#include <hip/hip_runtime.h>
#include <math.h>

#define H 64
#define N 50
#define S 50
#define B 1024
#define V 200000
#define VO (V - 1)   // 199999 output columns

// ---------------------------------------------------------------------------
// K1: h0 = emb[items]; hv_in = h0@ein_w + ein_b; hv_out = h0@eou_w + eou_b
// grid = B*N blocks, 64 threads (one per hidden dim)
// ---------------------------------------------------------------------------
__global__ __launch_bounds__(64) void k1_embed_lin(
    const int* __restrict__ items, const float* __restrict__ emb,
    const float* __restrict__ ein_w, const float* __restrict__ ein_b,
    const float* __restrict__ eou_w, const float* __restrict__ eou_b,
    float* __restrict__ h0, float* __restrict__ hv_in, float* __restrict__ hv_out)
{
    int bn = blockIdx.x;
    int j = threadIdx.x;
    __shared__ float hrow[H];
    int item = items[bn];
    float h = emb[(size_t)item * H + j];
    hrow[j] = h;
    h0[(size_t)bn * H + j] = h;
    __syncthreads();
    float si = ein_b[j], so = eou_b[j];
    #pragma unroll
    for (int k = 0; k < H; k++) {
        float x = hrow[k];
        si += x * ein_w[k * H + j];
        so += x * eou_w[k * H + j];
    }
    hv_in[(size_t)bn * H + j] = si;
    hv_out[(size_t)bn * H + j] = so;
}

// ---------------------------------------------------------------------------
// K2: input_in = ain @ hv_in + b_iah ; input_out = aou @ hv_out + b_oah
// grid = B*N blocks (one output row each), 64 threads
// ---------------------------------------------------------------------------
__global__ __launch_bounds__(64) void k2_adj(
    const float* __restrict__ ain, const float* __restrict__ aou,
    const float* __restrict__ hv_in, const float* __restrict__ hv_out,
    const float* __restrict__ b_iah, const float* __restrict__ b_oah,
    float* __restrict__ in_in, float* __restrict__ in_out)
{
    int bn = blockIdx.x;
    int b = bn / N;
    int j = threadIdx.x;
    const float* ar = ain + (size_t)bn * N;   // ain[b,n,:]
    const float* br = aou + (size_t)bn * N;
    const float* hin = hv_in + (size_t)b * N * H;
    const float* hou = hv_out + (size_t)b * N * H;
    float si = b_iah[j], so = b_oah[j];
    for (int m = 0; m < N; m++) {
        si += ar[m] * hin[m * H + j];
        so += br[m] * hou[m * H + j];
    }
    in_in[(size_t)bn * H + j] = si;
    in_out[(size_t)bn * H + j] = so;
}

// ---------------------------------------------------------------------------
// K3: GRU cell gates; h0 overwritten in place (each block touches only its row)
// ---------------------------------------------------------------------------
__global__ __launch_bounds__(64) void k3_gru(
    const float* __restrict__ in_in, const float* __restrict__ in_out,
    const float* __restrict__ igate_w, const float* __restrict__ igate_b,
    const float* __restrict__ hgate_w, const float* __restrict__ hgate_b,
    float* __restrict__ h0)
{
    int bn = blockIdx.x;
    int j = threadIdx.x;
    __shared__ float inp[2 * H];
    __shared__ float hrow[H];
    inp[j]     = in_in[(size_t)bn * H + j];
    inp[H + j] = in_out[(size_t)bn * H + j];
    hrow[j]    = h0[(size_t)bn * H + j];
    __syncthreads();
    float gr = igate_b[j], gi = igate_b[H + j], gn = igate_b[2 * H + j];
    for (int k = 0; k < 2 * H; k++) {
        float x = inp[k];
        const float* w = igate_w + (size_t)k * 3 * H;
        gr += x * w[j];
        gi += x * w[H + j];
        gn += x * w[2 * H + j];
    }
    float hr = hgate_b[j], hi = hgate_b[H + j], hn = hgate_b[2 * H + j];
    for (int k = 0; k < H; k++) {
        float x = hrow[k];
        const float* w = hgate_w + (size_t)k * 3 * H;
        hr += x * w[j];
        hi += x * w[H + j];
        hn += x * w[2 * H + j];
    }
    float resetg = 1.f / (1.f + expf(-(gr + hr)));
    float inputg = 1.f / (1.f + expf(-(gi + hi)));
    float newg = tanhf(gn + resetg * hn);
    float h = hrow[j];
    h0[(size_t)bn * H + j] = newg + inputg * (h - newg);
}

// ---------------------------------------------------------------------------
// K4: seq gather + attention readout -> a[B,H]
// grid = B blocks, 64 threads (one wave)
// ---------------------------------------------------------------------------
__global__ __launch_bounds__(64) void k4_attn(
    const int* __restrict__ alias_in, const int* __restrict__ mask,
    const float* __restrict__ h,
    const float* __restrict__ fc1_w, const float* __restrict__ fc1_b,
    const float* __restrict__ fc2_w, const float* __restrict__ fc2_b,
    const float* __restrict__ fc3_w, float* __restrict__ a)
{
    int b = blockIdx.x;
    int j = threadIdx.x;
    __shared__ float seq[S][H];
    __shared__ float q1s[H];
    const float* hb = h + (size_t)b * N * H;
    for (int s = 0; s < S; s++) {
        int node = alias_in[b * S + s];
        seq[s][j] = hb[(size_t)node * H + j];
    }
    int msum = 0;
    for (int s = 0; s < S; s++) msum += mask[b * S + s];
    int last = msum - 1;
    __syncthreads();
    float q1 = fc1_b[j];
    for (int k = 0; k < H; k++) q1 += seq[last][k] * fc1_w[k * H + j];
    q1s[j] = q1;
    __syncthreads();
    float f3 = fc3_w[j];
    float aj = 0.f;
    for (int s = 0; s < S; s++) {
        float q2 = fc2_b[j];
        for (int k = 0; k < H; k++) q2 += seq[s][k] * fc2_w[k * H + j];
        float v = (1.f / (1.f + expf(-(q1s[j] + q2)))) * f3;
        // full-wave butterfly sum -> alpha broadcast to all 64 lanes
        #pragma unroll
        for (int off = 1; off < 64; off <<= 1) v += __shfl_xor(v, off, 64);
        aj += v * seq[s][j] * (float)mask[b * S + s];
    }
    a[b * H + j] = aj;
}

// ---------------------------------------------------------------------------
// K5: out[b, v] = dot(a[b,:], emb[v+1,:])  -> [B, VO]
// 64x64 tiles, both operands staged in LDS (stride 68: float4-aligned,
// <=2-way bank conflicts), 4x4 register blocking per thread.
// grid = (ceil(VO/64), B/64), block = 256
// ---------------------------------------------------------------------------
__global__ __launch_bounds__(256) void k5_out(
    const float* __restrict__ a, const float* __restrict__ emb,
    float* __restrict__ out)
{
    __shared__ __align__(16) float As[64][68];
    __shared__ __align__(16) float Es[64][68];
    int tid = threadIdx.x;
    int tx = tid & 15, ty = tid >> 4;
    int v0 = blockIdx.x * 64;
    int b0 = blockIdx.y * 64;

    // cooperative staging: 64 rows x 16 float4 each, coalesced
    for (int idx = tid; idx < 64 * 16; idx += 256) {
        int row = idx >> 4, k4 = idx & 15;
        float4 av = *(const float4*)(a + (size_t)(b0 + row) * H + k4 * 4);
        *(float4*)&As[row][k4 * 4] = av;
        int v = v0 + row;
        float4 ev = make_float4(0.f, 0.f, 0.f, 0.f);
        if (v < VO) ev = *(const float4*)(emb + (size_t)(v + 1) * H + k4 * 4);
        *(float4*)&Es[row][k4 * 4] = ev;
    }
    __syncthreads();

    float acc[4][4] = {};
    #pragma unroll 4
    for (int k4 = 0; k4 < 16; k4++) {
        float4 af[4], ef[4];
        #pragma unroll
        for (int i = 0; i < 4; i++)
            af[i] = *(const float4*)&As[ty + 16 * i][k4 * 4];
        #pragma unroll
        for (int jj = 0; jj < 4; jj++)
            ef[jj] = *(const float4*)&Es[tx + 16 * jj][k4 * 4];
        #pragma unroll
        for (int i = 0; i < 4; i++)
            #pragma unroll
            for (int jj = 0; jj < 4; jj++)
                acc[i][jj] += af[i].x * ef[jj].x + af[i].y * ef[jj].y +
                              af[i].z * ef[jj].z + af[i].w * ef[jj].w;
    }

    #pragma unroll
    for (int i = 0; i < 4; i++) {
        int b = b0 + ty + 16 * i;
        #pragma unroll
        for (int jj = 0; jj < 4; jj++) {
            int v = v0 + tx + 16 * jj;
            if (v < VO) out[(size_t)b * VO + v] = acc[i][jj];
        }
    }
}

// ---------------------------------------------------------------------------
extern "C" void kernel_launch(void* const* d_in, const int* in_sizes, int n_in,
                              void* d_out, int out_size, void* d_ws, size_t ws_size,
                              hipStream_t stream)
{
    const int*   alias_in = (const int*)d_in[0];
    const float* ain      = (const float*)d_in[1];
    const float* aou      = (const float*)d_in[2];
    const int*   items    = (const int*)d_in[3];
    const int*   mask     = (const int*)d_in[4];
    // d_in[5] edge_index: unused
    const float* emb      = (const float*)d_in[6];
    const float* ein_w    = (const float*)d_in[7];
    const float* ein_b    = (const float*)d_in[8];
    const float* eou_w    = (const float*)d_in[9];
    const float* eou_b    = (const float*)d_in[10];
    const float* b_iah    = (const float*)d_in[11];
    const float* b_oah    = (const float*)d_in[12];
    const float* igate_w  = (const float*)d_in[13];
    const float* igate_b  = (const float*)d_in[14];
    const float* hgate_w  = (const float*)d_in[15];
    const float* hgate_b  = (const float*)d_in[16];
    const float* fc1_w    = (const float*)d_in[17];
    const float* fc1_b    = (const float*)d_in[18];
    const float* fc2_w    = (const float*)d_in[19];
    const float* fc2_b    = (const float*)d_in[20];
    const float* fc3_w    = (const float*)d_in[21];

    float* out = (float*)d_out;

    // Intermediates live inside d_out: all dead before K5 rewrites it.
    // 5 x B*N*H floats = 16.4M floats << out_size (204.8M floats).
    const size_t NH = (size_t)B * N * H;
    float* h0     = out;           // overwritten in place by K3 with new h
    float* hv_in  = h0 + NH;
    float* hv_out = hv_in + NH;
    float* in_in  = hv_out + NH;
    float* in_out = in_in + NH;
    float* a      = (float*)d_ws;  // [B,H] must survive K5 -> workspace

    k1_embed_lin<<<B * N, 64, 0, stream>>>(items, emb, ein_w, ein_b, eou_w, eou_b,
                                           h0, hv_in, hv_out);
    k2_adj<<<B * N, 64, 0, stream>>>(ain, aou, hv_in, hv_out, b_iah, b_oah,
                                     in_in, in_out);
    k3_gru<<<B * N, 64, 0, stream>>>(in_in, in_out, igate_w, igate_b,
                                     hgate_w, hgate_b, h0);
    k4_attn<<<B, 64, 0, stream>>>(alias_in, mask, h0, fc1_w, fc1_b,
                                  fc2_w, fc2_b, fc3_w, a);
    dim3 g5((VO + 63) / 64, B / 64);
    k5_out<<<g5, 256, 0, stream>>>(a, emb, out);
}